// Round 6
// baseline (251.594 us; speedup 1.0000x reference)
//
#include <hip/hip_runtime.h>

#define H 1024
#define E 64
#define BT 128
#define THETA 1e-4f    // relative p-gap risk threshold (~3-6x margin over split-bf16 error tail)

typedef __attribute__((ext_vector_type(4))) float f4;
typedef __attribute__((ext_vector_type(16))) float f32x16;
typedef __bf16 bf16x8 __attribute__((ext_vector_type(8)));
typedef unsigned int u32;
typedef __attribute__((ext_vector_type(4))) u32 u32x4;

__device__ __forceinline__ u32 cvtpk_bf16(float a, float b) {
    u32 r;
    asm("v_cvt_pk_bf16_f32 %0, %1, %2" : "=v"(r) : "v"(a), "v"(b));
    return r;
}
__device__ __forceinline__ float asfloat(u32 u) { union { u32 u; float f; } c; c.u = u; return c.f; }

// split 8 fp32 (k-ascending: a.xyzw, b.xyzw) into packed bf16-hi (RNE) and bf16-lo residual
__device__ __forceinline__ void split8(f4 a, f4 b, u32x4& hi, u32x4& lo) {
    float x0[4] = {a.x, a.z, b.x, b.z};
    float x1[4] = {a.y, a.w, b.y, b.w};
    #pragma unroll
    for (int i = 0; i < 4; ++i) {
        u32 h = cvtpk_bf16(x0[i], x1[i]);
        float r0 = x0[i] - asfloat(h << 16);
        float r1 = x1[i] - asfloat(h & 0xFFFF0000u);
        hi[i] = h;
        lo[i] = cvtpk_bf16(r0, r1);
    }
}

// async global->LDS, 16B per lane; LDS dest = wave-uniform base + lane*16
__device__ __forceinline__ void async16(const void* g, void* l) {
    __builtin_amdgcn_global_load_lds(
        (const __attribute__((address_space(1))) unsigned int*)g,
        (__attribute__((address_space(3))) unsigned int*)l,
        16, 0, 0);
}

// =====================================================================
// Pass A (round 6): 128 tokens x 64 experts per block, 1024 threads =
// 16 waves (4 token-quadrants x 2 expert-halves x 2 K-halves), grid 256
// = 1 block/CU. Byte-bound model (R2/R4 evidence: chunk time scales
// with chunk BYTES at ~13.4 B/cy/CU): minimize bytes on the async path.
//  - A (hs tile) ONLY is staged: 3 x 16 KB LDS buffers, K-chunks of 32,
//    depth-2 prefetch, counted "s_waitcnt vmcnt(3)" (never 0 mid-loop).
//  - B (wt) goes DIRECT global->register, one chunk ahead; its 8 KB
//    chunk-window is L1/L2-resident and shared by the 4 tq-waves, so it
//    stays off the MSHR-bound async stream. Compiler-counted waits for
//    B-use keep A-prefetches in flight (B issued before stage(c+2)).
//  - wt re-read traffic: 512 blocks*256KB (R4) -> 256 blocks*256KB.
// Source-side XOR swizzle (f4-slot j ^= row&7, 8 slots per 128 B row)
// keeps ds_read_b128 conflict-free. Split-bf16 MFMA unchanged
// (hi*hi -> acc0, hi*lo + lo*hi -> acc1). K-half combine via LDS
// float atomics (no P2 array): fits 48 KB static LDS.
// LDS: buf b at b*16384 B: A[128][32]f32. tail overlay: S[128][68] @f0,
// recip @f8704, hist @f8832, pi14[14][64] @f8896.
// =====================================================================
__global__ __launch_bounds__(1024, 4)
void gate_main(const float* __restrict__ hs, const float* __restrict__ wt,
               float* __restrict__ out, float* __restrict__ pi_ws,
               float* __restrict__ ce_ws, unsigned int* __restrict__ risk_cnt,
               unsigned int* __restrict__ risk_list, unsigned int risk_cap,
               int n_tokens) {
    __shared__ float smem[12288];                 // 48 KB
    const int t = threadIdx.x;
    const int wave = t >> 6, lane = t & 63;
    const int tok_base = blockIdx.x * BT;
    char* sb = (char*)smem;

    // ---- staging constants: thread t owns A row t>>3 (0..127), slot t&7
    const int srow = t >> 3;
    const int srcj = (t & 7) ^ (srow & 7);
    const float* gA = hs + (size_t)(tok_base + srow) * H + srcj * 4;
    const int sdest = wave << 10;                 // wave-uniform LDS base (bytes)

    // ---- wave roles: tq (token quadrant), ch (expert half), kh2 (K half)
    const int lr = lane & 31, kh = lane >> 5;
    const int tq = wave & 3, ch = (wave >> 2) & 1, kh2 = wave >> 3;
    const int wrow = tq * 32, wcol = ch * 32;
    const int arow = wrow + lr;
    const int s0 = kh2 * 4 + kh * 2;              // f4 slot of this lane's 8 k
    const int aoff0 = arow * 128 + (((s0    ) ^ (arow & 7)) << 4);
    const int aoff1 = arow * 128 + (((s0 + 1) ^ (arow & 7)) << 4);
    const float* gB = wt + (size_t)(wcol + lr) * H + kh2 * 16 + kh * 8;

    f32x16 acc0, acc1;
    #pragma unroll
    for (int i = 0; i < 16; ++i) { acc0[i] = 0.f; acc1[i] = 0.f; }

    auto stage = [&](int c) {                     // 1 async16 per thread
        char* bb = sb + (c % 3) * 16384;
        async16(gA + c * 32, bb + sdest);
    };

    // ---- B register double-buffer (named regs: no runtime indexing)
    f4 b0a, b1a, b0b, b1b;

    // ---- prologue: 2 A-chunks in flight + B(0) in regs
    stage(0); stage(1);
    b0a = *(const f4*)(gB);
    b1a = *(const f4*)(gB + 4);

    #pragma unroll 2
    for (int c = 0; c < 32; ++c) {
        __builtin_amdgcn_sched_barrier(0);
        // retire own stage(c); keep B(c) + stage(c+1) in flight
        if (c < 31) { asm volatile("s_waitcnt vmcnt(3)" ::: "memory"); }
        else        { asm volatile("s_waitcnt vmcnt(2)" ::: "memory"); }
        __builtin_amdgcn_s_barrier();             // A chunk c published
        __builtin_amdgcn_sched_barrier(0);
        if (c + 1 < 32) {                         // B one chunk ahead
            const float* p = gB + (c + 1) * 32;
            if ((c & 1) == 0) { b0b = *(const f4*)p; b1b = *(const f4*)(p + 4); }
            else              { b0a = *(const f4*)p; b1a = *(const f4*)(p + 4); }
        }
        if (c + 2 < 32) stage(c + 2);             // overwrites buf (c-1)%3: safe
        __builtin_amdgcn_sched_barrier(0);
        const char* cb = sb + (c % 3) * 16384;
        f4 a0 = *(const f4*)(cb + aoff0);
        f4 a1 = *(const f4*)(cb + aoff1);
        u32x4 ahp, alp, bhp, blp;
        split8(a0, a1, ahp, alp);
        if ((c & 1) == 0) split8(b0a, b1a, bhp, blp);
        else              split8(b0b, b1b, bhp, blp);
        const bf16x8 ah = __builtin_bit_cast(bf16x8, ahp);
        const bf16x8 al = __builtin_bit_cast(bf16x8, alp);
        const bf16x8 bh = __builtin_bit_cast(bf16x8, bhp);
        const bf16x8 bl = __builtin_bit_cast(bf16x8, blp);
        acc0 = __builtin_amdgcn_mfma_f32_32x32x16_bf16(ah, bh, acc0, 0, 0, 0);
        acc1 = __builtin_amdgcn_mfma_f32_32x32x16_bf16(ah, bl, acc1, 0, 0, 0);
        acc1 = __builtin_amdgcn_mfma_f32_32x32x16_bf16(al, bh, acc1, 0, 0, 0);
    }
    __syncthreads();                              // buffers dead from here

    float* S = smem;                              // [128][68]
    f4* S4 = (f4*)smem;
    float* recip = smem + 8704;                   // [128]
    float* hist  = smem + 8832;                   // [64]
    float* pi14  = smem + 8896;                   // [14][64]

    // ---- write logits: kh2=0 stores, kh2=1 adds via LDS atomics ----
    {
        float vs[16];
        #pragma unroll
        for (int i = 0; i < 16; ++i) vs[i] = acc0[i] + acc1[i];
        if (!kh2) {
            #pragma unroll
            for (int gq = 0; gq < 4; ++gq)
                #pragma unroll
                for (int qq = 0; qq < 4; ++qq) {
                    const int row = qq + gq * 8 + kh * 4;   // C/D layout (m74/m101)
                    S[(wrow + row) * 68 + wcol + lr] = vs[gq * 4 + qq];
                }
        }
        if (t < 64) hist[t] = 0.f;
        __syncthreads();
        if (kh2) {
            #pragma unroll
            for (int gq = 0; gq < 4; ++gq)
                #pragma unroll
                for (int qq = 0; qq < 4; ++qq) {
                    const int row = qq + gq * 8 + kh * 4;
                    atomicAdd(&S[(wrow + row) * 68 + wcol + lr], vs[gq * 4 + qq]);
                }
        }
    }
    __syncthreads();

    // ---- p = exp(l - m) in-place, 4 threads per token (threads 0..511) ----
    if (t < 512) {
        const int tok = t >> 2, q = t & 3;
        f4 v[4];
        #pragma unroll
        for (int c2 = 0; c2 < 4; ++c2) v[c2] = S4[tok * 17 + q * 4 + c2];
        float m = v[0].x;
        #pragma unroll
        for (int c2 = 0; c2 < 4; ++c2)
            m = fmaxf(m, fmaxf(fmaxf(v[c2].x, v[c2].y), fmaxf(v[c2].z, v[c2].w)));
        m = fmaxf(m, __shfl_xor(m, 1, 64));
        m = fmaxf(m, __shfl_xor(m, 2, 64));
        float lsum = 0.f;
        #pragma unroll
        for (int c2 = 0; c2 < 4; ++c2) {
            v[c2].x = __expf(v[c2].x - m); v[c2].y = __expf(v[c2].y - m);
            v[c2].z = __expf(v[c2].z - m); v[c2].w = __expf(v[c2].w - m);
            lsum += (v[c2].x + v[c2].y) + (v[c2].z + v[c2].w);
        }
        #pragma unroll
        for (int c2 = 0; c2 < 4; ++c2) S4[tok * 17 + q * 4 + c2] = v[c2];
        lsum += __shfl_xor(lsum, 1, 64);
        lsum += __shfl_xor(lsum, 2, 64);
        if (q == 0) recip[tok] = 1.0f / lsum;
    }
    __syncthreads();

    // ---- SEL (waves 14,15: thread-per-token) + pi partials (waves 0..13) ----
    if (wave >= 14) {
        const int tok = (wave - 14) * 64 + lane;
        const int tok_g = tok_base + tok;
        float val[9]; int idx[9];
        #pragma unroll
        for (int r = 0; r < 9; ++r) { val[r] = -1.f; idx[r] = 0; }
        #pragma unroll
        for (int c2 = 0; c2 < 16; ++c2) {
            f4 v = S4[tok * 17 + c2];
            float e4[4] = {v.x, v.y, v.z, v.w};
            #pragma unroll
            for (int u = 0; u < 4; ++u) {
                float cv = e4[u]; int ci = c2 * 4 + u;
                #pragma unroll
                for (int r = 0; r < 9; ++r) {
                    const bool g = cv > val[r];    // strict: stream order = stable ties
                    const float tv = val[r]; const int ti = idx[r];
                    val[r] = g ? cv : tv;  idx[r] = g ? ci : ti;
                    cv = g ? tv : cv;      ci = g ? ti : ci;
                }
            }
        }
        const float s8 = ((val[0] + val[1]) + (val[2] + val[3]))
                       + ((val[4] + val[5]) + (val[6] + val[7]));
        const float wsum = s8 + 1e-20f;
        f4* out4 = (f4*)out;
        f4 o;
        o.x = (float)idx[0]; o.y = (float)idx[1]; o.z = (float)idx[2]; o.w = (float)idx[3];
        out4[(size_t)tok_g * 2] = o;
        o.x = (float)idx[4]; o.y = (float)idx[5]; o.z = (float)idx[6]; o.w = (float)idx[7];
        out4[(size_t)tok_g * 2 + 1] = o;
        const size_t wb = (size_t)n_tokens * 2;
        o.x = val[0] / wsum; o.y = val[1] / wsum; o.z = val[2] / wsum; o.w = val[3] / wsum;
        out4[wb + (size_t)tok_g * 2] = o;
        o.x = val[4] / wsum; o.y = val[5] / wsum; o.z = val[6] / wsum; o.w = val[7] / wsum;
        out4[wb + (size_t)tok_g * 2 + 1] = o;
        #pragma unroll
        for (int r = 0; r < 8; ++r) atomicAdd(&hist[idx[r]], 1.0f);
        float ming = 1e30f;
        #pragma unroll
        for (int r = 0; r < 8; ++r)
            ming = fminf(ming, (val[r] - val[r + 1]) / fmaxf(val[r], 1e-30f));
        if (ming < THETA) {
            unsigned int pos = atomicAdd(risk_cnt, 1u);
            if (pos < risk_cap) risk_list[pos] = (unsigned int)tok_g;
        }
    } else {
        const int e = lane;
        const int t0 = (wave * 128) / 14;
        const int t1 = ((wave + 1) * 128) / 14;
        float part = 0.f;
        for (int tok = t0; tok < t1; ++tok)
            part = fmaf(S[tok * 68 + e], recip[tok], part);
        pi14[wave * 64 + e] = part;
    }
    __syncthreads();
    // ---- 8-replica accumulators: atomic contention / 8 ----
    const int rep = (blockIdx.x & 7) << 6;
    if (t < 64) {
        float p = 0.f;
        #pragma unroll
        for (int i = 0; i < 14; ++i) p += pi14[i * 64 + t];
        atomicAdd(&pi_ws[rep + t], p);
    } else if (t < 128) {
        atomicAdd(&ce_ws[rep + (t - 64)], hist[t - 64]);
    }
}

// =====================================================================
// Pass B: fp64 recompute of risky tokens (exact ranking); block 0 also
// finalizes the aux loss (sums the 8 pi/ce replicas).
// =====================================================================
__global__ __launch_bounds__(256)
void gate_fixup(const float* __restrict__ hs, const float* __restrict__ wt,
                float* __restrict__ out, const unsigned int* __restrict__ risk_cnt,
                const unsigned int* __restrict__ risk_list, unsigned int risk_cap,
                int n_tokens, const float* __restrict__ pi_ws,
                const float* __restrict__ ce_ws) {
    __shared__ float hrow[H];
    __shared__ double red[256];
    const int t = threadIdx.x;

    if (blockIdx.x == 0 && t < 64) {              // aux loss (wave 0 only)
        double pi = 0.0, ce = 0.0;
        #pragma unroll
        for (int rp = 0; rp < 8; ++rp) {
            pi += (double)pi_ws[rp * 64 + t];
            ce += (double)ce_ws[rp * 64 + t];
        }
        pi /= (double)n_tokens;
        ce /= ((double)n_tokens * 8.0);
        double term = pi * ce * 64.0;
        #pragma unroll
        for (int off = 32; off > 0; off >>= 1) term += __shfl_xor(term, off, 64);
        if (t == 0) out[(size_t)n_tokens * 16] = (float)(term * 0.01);
    }

    unsigned int cnt = *risk_cnt;
    if (cnt > risk_cap) cnt = risk_cap;

    for (unsigned int u = blockIdx.x; u < cnt; u += gridDim.x) {
        const int tok = (int)risk_list[u];
        ((float4*)hrow)[t] = ((const float4*)(hs + (size_t)tok * H))[t];
        __syncthreads();

        const int e = t >> 2, sl = t & 3;
        const float4* wp = (const float4*)wt + (size_t)e * 256;
        const float4* hp = (const float4*)hrow;
        double acc = 0.0;
        #pragma unroll 8
        for (int k4 = 0; k4 < 64; ++k4) {
            float4 wv = wp[k4 * 4 + sl];
            float4 hv = hp[k4 * 4 + sl];
            acc = fma((double)wv.x, (double)hv.x, acc);
            acc = fma((double)wv.y, (double)hv.y, acc);
            acc = fma((double)wv.z, (double)hv.z, acc);
            acc = fma((double)wv.w, (double)hv.w, acc);
        }
        red[t] = acc;
        __syncthreads();

        if (t < 64) {
            const int lane = t;
            double lg = red[t * 4] + red[t * 4 + 1] + red[t * 4 + 2] + red[t * 4 + 3];
            double m = lg;
            #pragma unroll
            for (int off = 32; off > 0; off >>= 1) {
                double o = __shfl_xor(m, off, 64);
                m = (o > m) ? o : m;
            }
            const double p = exp(lg - m);
            double v = lg, psum = 0.0, mypv = 0.0;
            int myidx = 0;
            for (int r = 0; r < 8; ++r) {
                double bv = v; int bi = lane;
                #pragma unroll
                for (int off = 32; off > 0; off >>= 1) {
                    double ov = __shfl_xor(bv, off, 64);
                    int    oi = __shfl_xor(bi, off, 64);
                    if (ov > bv || (ov == bv && oi < bi)) { bv = ov; bi = oi; }
                }
                double pw = __shfl(p, bi, 64);
                psum += pw;
                if (lane == r) { myidx = bi; mypv = pw; }
                if (lane == bi) v = -1e300;
            }
            const double wsum = psum + 1e-20;
            if (lane < 8) {
                out[(size_t)tok * 8 + lane] = (float)myidx;
                out[(size_t)n_tokens * 8 + (size_t)tok * 8 + lane] = (float)(mypv / wsum);
            }
        }
        __syncthreads();
    }
}

extern "C" void kernel_launch(void* const* d_in, const int* in_sizes, int n_in,
                              void* d_out, int out_size, void* d_ws, size_t ws_size,
                              hipStream_t stream) {
    const float* hs = (const float*)d_in[0];
    const float* wt = (const float*)d_in[1];
    float* out = (float*)d_out;
    const int n_tokens = in_sizes[0] / H;         // 32768

    // ws layout: pi[8][64] @0 (2048B), ce[8][64] @2048, risk_cnt @4096,
    //            risk_list @4608
    float* pi_ws = (float*)d_ws;
    float* ce_ws = (float*)((char*)d_ws + 2048);
    unsigned int* risk_cnt  = (unsigned int*)((char*)d_ws + 4096);
    unsigned int* risk_list = (unsigned int*)((char*)d_ws + 4608);
    unsigned int risk_cap = (unsigned int)((ws_size > 4608 ? (ws_size - 4608) : 0) / 4);
    if (risk_cap > (unsigned int)n_tokens) risk_cap = (unsigned int)n_tokens;

    size_t zbytes = ws_size < 4608 ? ws_size : 4608;
    hipMemsetAsync(d_ws, 0, zbytes, stream);

    gate_main<<<n_tokens / BT, 1024, 0, stream>>>(hs, wt, out, pi_ws, ce_ws,
                                                  risk_cnt, risk_list, risk_cap, n_tokens);
    gate_fixup<<<256, 256, 0, stream>>>(hs, wt, out, risk_cnt, risk_list, risk_cap,
                                        n_tokens, pi_ws, ce_ws);
}

// Round 7
// 242.494 us; speedup vs baseline: 1.0375x; 1.0375x over previous
//
#include <hip/hip_runtime.h>

#define H 1024
#define E 64
#define BT 64
#define THETA 1e-4f    // relative p-gap risk threshold (~3-6x margin over split-bf16 error tail)

typedef __attribute__((ext_vector_type(4))) float f4;
typedef __attribute__((ext_vector_type(16))) float f32x16;
typedef __bf16 bf16x8 __attribute__((ext_vector_type(8)));
typedef unsigned int u32;
typedef __attribute__((ext_vector_type(4))) u32 u32x4;

__device__ __forceinline__ u32 cvtpk_bf16(float a, float b) {
    u32 r;
    asm("v_cvt_pk_bf16_f32 %0, %1, %2" : "=v"(r) : "v"(a), "v"(b));
    return r;
}
__device__ __forceinline__ float asfloat(u32 u) { union { u32 u; float f; } c; c.u = u; return c.f; }

// split 8 fp32 (k-ascending: a.xyzw, b.xyzw) into packed bf16-hi (RNE) and bf16-lo residual
__device__ __forceinline__ void split8(f4 a, f4 b, u32x4& hi, u32x4& lo) {
    float x0[4] = {a.x, a.z, b.x, b.z};
    float x1[4] = {a.y, a.w, b.y, b.w};
    #pragma unroll
    for (int i = 0; i < 4; ++i) {
        u32 h = cvtpk_bf16(x0[i], x1[i]);
        float r0 = x0[i] - asfloat(h << 16);
        float r1 = x1[i] - asfloat(h & 0xFFFF0000u);
        hi[i] = h;
        lo[i] = cvtpk_bf16(r0, r1);
    }
}

// async global->LDS, 16B per lane; LDS dest = wave-uniform base + lane*16
__device__ __forceinline__ void async16(const void* g, void* l) {
    __builtin_amdgcn_global_load_lds(
        (const __attribute__((address_space(1))) unsigned int*)g,
        (__attribute__((address_space(3))) unsigned int*)l,
        16, 0, 0);
}

// =====================================================================
// Pass A (round 7) = round-4 structure (best measured: 8 waves, 2
// blocks/CU, 4 LDS buffers, depth-3 counted-vmcnt pipeline) with ONE
// change: B (wt) leaves the async global_load_lds path and is loaded
// DIRECT to registers one chunk ahead (named reg pairs, parity-static).
// Async staged bytes/CU drop 2x (A only: 1 async16/thread/chunk);
// B's 8 KB/chunk window is L1/L2-resident (re-read by 512 blocks).
// vmcnt literals re-derived for the mixed load stream via the suffix
// rule (N = count of loads issued after the stage being retired):
// prologue B0,s0,s1,s2 -> c=0:2, c=1:4, c in [2,29]:6, c=30:5, c=31:4.
// Source-side XOR swizzle (f4-slot j ^= row&7) keeps ds_read_b128
// conflict-free; split-bf16 MFMA unchanged. K-half combine via LDS
// atomicAdd (R6-validated) -> everything fits 32 KB static LDS.
// LDS: buf b at b*8192 B: A[64][32]f32. tail overlay: S[64][68] @f0,
// recip @f4352, hist @f4416, pi7[7][64] @f4480.
// =====================================================================
__global__ __launch_bounds__(512, 4)
void gate_main(const float* __restrict__ hs, const float* __restrict__ wt,
               float* __restrict__ out, float* __restrict__ pi_ws,
               float* __restrict__ ce_ws, unsigned int* __restrict__ risk_cnt,
               unsigned int* __restrict__ risk_list, unsigned int risk_cap,
               int n_tokens) {
    __shared__ float smem[8192];                  // 32 KB
    const int t = threadIdx.x;
    const int wave = t >> 6, lane = t & 63;
    const int tok_base = blockIdx.x * BT;
    char* sb = (char*)smem;

    // ---- staging constants: thread t owns A row t>>3, slot t&7, swizzled source
    const int srow = t >> 3;                      // 0..63
    const int srcj = (t & 7) ^ (srow & 7);
    const float* gA = hs + (size_t)(tok_base + srow) * H + srcj * 4;
    const int sdest = wave << 10;                 // wave-uniform LDS base (bytes)

    // ---- mfma constants: wave -> quadrant (q4) x K-half (kh2)
    const int lr = lane & 31, kh = lane >> 5;
    const int q4 = wave & 3, kh2 = wave >> 2;
    const int wrow = (q4 >> 1) * 32;              // token base of quadrant
    const int wcol = (q4 & 1) * 32;               // expert base of quadrant
    const int arow = wrow + lr;
    const int s0 = kh2 * 4 + kh * 2;              // even f4 slot of this lane's 8 k
    const int aoff0 = arow * 128 + (((s0    ) ^ (arow & 7)) << 4);
    const int aoff1 = arow * 128 + (((s0 + 1) ^ (arow & 7)) << 4);
    const float* gBb = wt + (size_t)(wcol + lr) * H + s0 * 4;   // this lane's B stream

    f32x16 acc0, acc1;
    #pragma unroll
    for (int i = 0; i < 16; ++i) { acc0[i] = 0.f; acc1[i] = 0.f; }

    auto stage = [&](int c) {                     // 1 async16 per thread
        char* bb = sb + (c & 3) * 8192;
        async16(gA + c * 32, bb + sdest);
    };
    auto compute = [&](int c, f4 bb0, f4 bb1) {   // one 16-K MFMA step per wave
        const char* cb = sb + (c & 3) * 8192;
        f4 a0 = *(const f4*)(cb + aoff0);
        f4 a1 = *(const f4*)(cb + aoff1);
        u32x4 ahp, alp, bhp, blp;
        split8(a0, a1, ahp, alp);
        split8(bb0, bb1, bhp, blp);
        const bf16x8 ah = __builtin_bit_cast(bf16x8, ahp);
        const bf16x8 al = __builtin_bit_cast(bf16x8, alp);
        const bf16x8 bh = __builtin_bit_cast(bf16x8, bhp);
        const bf16x8 bl = __builtin_bit_cast(bf16x8, blp);
        acc0 = __builtin_amdgcn_mfma_f32_32x32x16_bf16(ah, bh, acc0, 0, 0, 0);
        acc1 = __builtin_amdgcn_mfma_f32_32x32x16_bf16(ah, bl, acc1, 0, 0, 0);
        acc1 = __builtin_amdgcn_mfma_f32_32x32x16_bf16(al, bh, acc1, 0, 0, 0);
    };

    // ---- prologue: B(0) first, then 3 A-chunks in flight
    f4 b0a = *(const f4*)(gBb);
    f4 b1a = *(const f4*)(gBb + 4);
    f4 b0b, b1b;
    stage(0); stage(1); stage(2);

    // ---- c = 0 (youngers of s0: s1,s2 -> vmcnt(2); also retires B0)
    asm volatile("s_waitcnt vmcnt(2)" ::: "memory");
    __builtin_amdgcn_s_barrier();
    __builtin_amdgcn_sched_barrier(0);
    b0b = *(const f4*)(gBb + 32); b1b = *(const f4*)(gBb + 36);   // B(1)
    stage(3);
    __builtin_amdgcn_sched_barrier(0);
    compute(0, b0a, b1a);

    // ---- c = 1 (youngers of s1: s2,B1x2,s3 -> vmcnt(4))
    asm volatile("s_waitcnt vmcnt(4)" ::: "memory");
    __builtin_amdgcn_s_barrier();
    __builtin_amdgcn_sched_barrier(0);
    b0a = *(const f4*)(gBb + 64); b1a = *(const f4*)(gBb + 68);   // B(2)
    stage(4);
    __builtin_amdgcn_sched_barrier(0);
    compute(1, b0b, b1b);

    // ---- main loop c = 2..29 (youngers of s(c) = 6: B(c-1)x2? no —
    //      B(c)x2, s(c+1), s(c+2), B(c-1)x2 pattern sums to 6; see header)
    #pragma unroll 2
    for (int c = 2; c < 30; ++c) {
        asm volatile("s_waitcnt vmcnt(6)" ::: "memory");
        __builtin_amdgcn_s_barrier();
        __builtin_amdgcn_sched_barrier(0);
        const float* p = gBb + (c + 1) * 32;                      // B(c+1)
        if ((c & 1) == 0) { b0b = *(const f4*)p; b1b = *(const f4*)(p + 4); }
        else              { b0a = *(const f4*)p; b1a = *(const f4*)(p + 4); }
        if (c < 29) stage(c + 3);
        __builtin_amdgcn_sched_barrier(0);
        if ((c & 1) == 0) compute(c, b0a, b1a);
        else              compute(c, b0b, b1b);
    }

    // ---- c = 30 (youngers of s30: B29x2,s31,B30x2 -> vmcnt(5))
    asm volatile("s_waitcnt vmcnt(5)" ::: "memory");
    __builtin_amdgcn_s_barrier();
    __builtin_amdgcn_sched_barrier(0);
    b0b = *(const f4*)(gBb + 31 * 32); b1b = *(const f4*)(gBb + 31 * 32 + 4); // B(31)
    __builtin_amdgcn_sched_barrier(0);
    compute(30, b0a, b1a);

    // ---- c = 31 (youngers of s31: B30x2,B31x2 -> vmcnt(4))
    asm volatile("s_waitcnt vmcnt(4)" ::: "memory");
    __builtin_amdgcn_s_barrier();
    __builtin_amdgcn_sched_barrier(0);
    compute(31, b0b, b1b);
    __syncthreads();                              // buffers dead from here

    float* S = smem;                              // [64][68]
    f4* S4 = (f4*)smem;
    float* recip = smem + 4352;
    float* hist  = smem + 4416;
    float* pi7   = smem + 4480;                   // [7][64]

    // ---- combine K-halves: kh2=0 stores, kh2=1 adds via LDS atomics ----
    {
        float vs[16];
        #pragma unroll
        for (int i = 0; i < 16; ++i) vs[i] = acc0[i] + acc1[i];
        if (!kh2) {
            #pragma unroll
            for (int gq = 0; gq < 4; ++gq)
                #pragma unroll
                for (int qq = 0; qq < 4; ++qq) {
                    const int row = qq + gq * 8 + kh * 4;   // C/D layout (m74/m101)
                    S[(wrow + row) * 68 + wcol + lr] = vs[gq * 4 + qq];
                }
        }
        if (t < 64) hist[t] = 0.f;
        __syncthreads();
        if (kh2) {
            #pragma unroll
            for (int gq = 0; gq < 4; ++gq)
                #pragma unroll
                for (int qq = 0; qq < 4; ++qq) {
                    const int row = qq + gq * 8 + kh * 4;
                    atomicAdd(&S[(wrow + row) * 68 + wcol + lr], vs[gq * 4 + qq]);
                }
        }
    }
    __syncthreads();

    // ---- p = exp(l - m) in-place, 4 threads per token (threads 0..255) ----
    if (t < 256) {
        const int tok = t >> 2, q = t & 3;
        f4 v[4];
        #pragma unroll
        for (int c2 = 0; c2 < 4; ++c2) v[c2] = S4[tok * 17 + q * 4 + c2];
        float m = v[0].x;
        #pragma unroll
        for (int c2 = 0; c2 < 4; ++c2)
            m = fmaxf(m, fmaxf(fmaxf(v[c2].x, v[c2].y), fmaxf(v[c2].z, v[c2].w)));
        m = fmaxf(m, __shfl_xor(m, 1, 64));
        m = fmaxf(m, __shfl_xor(m, 2, 64));
        float lsum = 0.f;
        #pragma unroll
        for (int c2 = 0; c2 < 4; ++c2) {
            v[c2].x = __expf(v[c2].x - m); v[c2].y = __expf(v[c2].y - m);
            v[c2].z = __expf(v[c2].z - m); v[c2].w = __expf(v[c2].w - m);
            lsum += (v[c2].x + v[c2].y) + (v[c2].z + v[c2].w);
        }
        #pragma unroll
        for (int c2 = 0; c2 < 4; ++c2) S4[tok * 17 + q * 4 + c2] = v[c2];
        lsum += __shfl_xor(lsum, 1, 64);
        lsum += __shfl_xor(lsum, 2, 64);
        if (q == 0) recip[tok] = 1.0f / lsum;
    }
    __syncthreads();

    // ---- SEL (one wave, thread-per-token) + pi partials (other 7 waves) ----
    const int selw = blockIdx.x & 7;
    if (wave == selw) {
        const int tok = lane;
        const int tok_g = tok_base + tok;
        float val[9]; int idx[9];
        #pragma unroll
        for (int r = 0; r < 9; ++r) { val[r] = -1.f; idx[r] = 0; }
        #pragma unroll
        for (int c2 = 0; c2 < 16; ++c2) {
            f4 v = S4[tok * 17 + c2];
            float e4[4] = {v.x, v.y, v.z, v.w};
            #pragma unroll
            for (int u = 0; u < 4; ++u) {
                float cv = e4[u]; int ci = c2 * 4 + u;
                #pragma unroll
                for (int r = 0; r < 9; ++r) {
                    const bool g = cv > val[r];    // strict: stream order = stable ties
                    const float tv = val[r]; const int ti = idx[r];
                    val[r] = g ? cv : tv;  idx[r] = g ? ci : ti;
                    cv = g ? tv : cv;      ci = g ? ti : ci;
                }
            }
        }
        const float s8 = ((val[0] + val[1]) + (val[2] + val[3]))
                       + ((val[4] + val[5]) + (val[6] + val[7]));
        const float wsum = s8 + 1e-20f;
        f4* out4 = (f4*)out;
        f4 o;
        o.x = (float)idx[0]; o.y = (float)idx[1]; o.z = (float)idx[2]; o.w = (float)idx[3];
        out4[(size_t)tok_g * 2] = o;
        o.x = (float)idx[4]; o.y = (float)idx[5]; o.z = (float)idx[6]; o.w = (float)idx[7];
        out4[(size_t)tok_g * 2 + 1] = o;
        const size_t wb = (size_t)n_tokens * 2;
        o.x = val[0] / wsum; o.y = val[1] / wsum; o.z = val[2] / wsum; o.w = val[3] / wsum;
        out4[wb + (size_t)tok_g * 2] = o;
        o.x = val[4] / wsum; o.y = val[5] / wsum; o.z = val[6] / wsum; o.w = val[7] / wsum;
        out4[wb + (size_t)tok_g * 2 + 1] = o;
        #pragma unroll
        for (int r = 0; r < 8; ++r) atomicAdd(&hist[idx[r]], 1.0f);
        float ming = 1e30f;
        #pragma unroll
        for (int r = 0; r < 8; ++r)
            ming = fminf(ming, (val[r] - val[r + 1]) / fmaxf(val[r], 1e-30f));
        if (ming < THETA) {
            unsigned int pos = atomicAdd(risk_cnt, 1u);
            if (pos < risk_cap) risk_list[pos] = (unsigned int)tok_g;
        }
    } else {
        const int sev = ((wave - selw) & 7) - 1;          // 0..6
        const int e = lane;
        const int t0 = sev * 9;
        const int t1 = (sev == 6) ? 64 : (t0 + 9);
        float part = 0.f;
        for (int tok = t0; tok < t1; ++tok)
            part = fmaf(S[tok * 68 + e], recip[tok], part);
        pi7[sev * 64 + e] = part;
    }
    __syncthreads();
    // ---- 8-replica accumulators: atomic contention / 8 ----
    const int rep = (blockIdx.x & 7) << 6;
    if (t < 64) {
        const float p = ((pi7[t] + pi7[64 + t]) + (pi7[128 + t] + pi7[192 + t]))
                      + ((pi7[256 + t] + pi7[320 + t]) + pi7[384 + t]);
        atomicAdd(&pi_ws[rep + t], p);
    } else if (t < 128) {
        atomicAdd(&ce_ws[rep + (t - 64)], hist[t - 64]);
    }
}

// =====================================================================
// Pass B: fp64 recompute of risky tokens (exact ranking); block 0 also
// finalizes the aux loss (sums the 8 pi/ce replicas).
// =====================================================================
__global__ __launch_bounds__(256)
void gate_fixup(const float* __restrict__ hs, const float* __restrict__ wt,
                float* __restrict__ out, const unsigned int* __restrict__ risk_cnt,
                const unsigned int* __restrict__ risk_list, unsigned int risk_cap,
                int n_tokens, const float* __restrict__ pi_ws,
                const float* __restrict__ ce_ws) {
    __shared__ float hrow[H];
    __shared__ double red[256];
    const int t = threadIdx.x;

    if (blockIdx.x == 0 && t < 64) {              // aux loss (wave 0 only)
        double pi = 0.0, ce = 0.0;
        #pragma unroll
        for (int rp = 0; rp < 8; ++rp) {
            pi += (double)pi_ws[rp * 64 + t];
            ce += (double)ce_ws[rp * 64 + t];
        }
        pi /= (double)n_tokens;
        ce /= ((double)n_tokens * 8.0);
        double term = pi * ce * 64.0;
        #pragma unroll
        for (int off = 32; off > 0; off >>= 1) term += __shfl_xor(term, off, 64);
        if (t == 0) out[(size_t)n_tokens * 16] = (float)(term * 0.01);
    }

    unsigned int cnt = *risk_cnt;
    if (cnt > risk_cap) cnt = risk_cap;

    for (unsigned int u = blockIdx.x; u < cnt; u += gridDim.x) {
        const int tok = (int)risk_list[u];
        ((float4*)hrow)[t] = ((const float4*)(hs + (size_t)tok * H))[t];
        __syncthreads();

        const int e = t >> 2, sl = t & 3;
        const float4* wp = (const float4*)wt + (size_t)e * 256;
        const float4* hp = (const float4*)hrow;
        double acc = 0.0;
        #pragma unroll 8
        for (int k4 = 0; k4 < 64; ++k4) {
            float4 wv = wp[k4 * 4 + sl];
            float4 hv = hp[k4 * 4 + sl];
            acc = fma((double)wv.x, (double)hv.x, acc);
            acc = fma((double)wv.y, (double)hv.y, acc);
            acc = fma((double)wv.z, (double)hv.z, acc);
            acc = fma((double)wv.w, (double)hv.w, acc);
        }
        red[t] = acc;
        __syncthreads();

        if (t < 64) {
            const int lane = t;
            double lg = red[t * 4] + red[t * 4 + 1] + red[t * 4 + 2] + red[t * 4 + 3];
            double m = lg;
            #pragma unroll
            for (int off = 32; off > 0; off >>= 1) {
                double o = __shfl_xor(m, off, 64);
                m = (o > m) ? o : m;
            }
            const double p = exp(lg - m);
            double v = lg, psum = 0.0, mypv = 0.0;
            int myidx = 0;
            for (int r = 0; r < 8; ++r) {
                double bv = v; int bi = lane;
                #pragma unroll
                for (int off = 32; off > 0; off >>= 1) {
                    double ov = __shfl_xor(bv, off, 64);
                    int    oi = __shfl_xor(bi, off, 64);
                    if (ov > bv || (ov == bv && oi < bi)) { bv = ov; bi = oi; }
                }
                double pw = __shfl(p, bi, 64);
                psum += pw;
                if (lane == r) { myidx = bi; mypv = pw; }
                if (lane == bi) v = -1e300;
            }
            const double wsum = psum + 1e-20;
            if (lane < 8) {
                out[(size_t)tok * 8 + lane] = (float)myidx;
                out[(size_t)n_tokens * 8 + (size_t)tok * 8 + lane] = (float)(mypv / wsum);
            }
        }
        __syncthreads();
    }
}

extern "C" void kernel_launch(void* const* d_in, const int* in_sizes, int n_in,
                              void* d_out, int out_size, void* d_ws, size_t ws_size,
                              hipStream_t stream) {
    const float* hs = (const float*)d_in[0];
    const float* wt = (const float*)d_in[1];
    float* out = (float*)d_out;
    const int n_tokens = in_sizes[0] / H;         // 32768

    // ws layout: pi[8][64] @0 (2048B), ce[8][64] @2048, risk_cnt @4096,
    //            risk_list @4608
    float* pi_ws = (float*)d_ws;
    float* ce_ws = (float*)((char*)d_ws + 2048);
    unsigned int* risk_cnt  = (unsigned int*)((char*)d_ws + 4096);
    unsigned int* risk_list = (unsigned int*)((char*)d_ws + 4608);
    unsigned int risk_cap = (unsigned int)((ws_size > 4608 ? (ws_size - 4608) : 0) / 4);
    if (risk_cap > (unsigned int)n_tokens) risk_cap = (unsigned int)n_tokens;

    size_t zbytes = ws_size < 4608 ? ws_size : 4608;
    hipMemsetAsync(d_ws, 0, zbytes, stream);

    gate_main<<<n_tokens / BT, 512, 0, stream>>>(hs, wt, out, pi_ws, ce_ws,
                                                 risk_cnt, risk_list, risk_cap, n_tokens);
    gate_fixup<<<256, 256, 0, stream>>>(hs, wt, out, risk_cnt, risk_list, risk_cap,
                                        n_tokens, pi_ws, ce_ws);
}